// Round 2
// baseline (1285.377 us; speedup 1.0000x reference)
//
#include <hip/hip_runtime.h>
#include <hip/hip_bf16.h>
#include <cstdint>

// MoE SwiGLU: B=8 S=2048 D=1024 H=2048 E=8 K=2. T=16384 tokens.
// Routed (top-2 only) bf16-MFMA implementation; gating in fp32.
//
// R3: XOR-swizzled LDS layout (bank conflicts 2.4e8 -> 3.4e7).
// R5: fatter tiles. Profile showed gemm_act at 410us, MfmaUtil 30%,
// VALU 22%, HBM 14% -- LDS-read-bound: 16 ds_read_b128 (~192cy) vs
// 16 MFMA (~128cy) per wave per K-step (ratio 1.0). Fix: per-wave
// fragment reuse. gemm_act BN 64->128 (6 reads : 8 MFMA per ks),
// gemm_out BN 128->256 (same ratio). Sync structure + swizzle unchanged.

#define T_TOK 16384
#define DIM   1024
#define HID   2048
#define NEXP  8
#define MAX_TILES 264   // sum ceil(Ne/128) <= 32768/128 + 8

typedef __bf16 bf16;
typedef bf16  bf16x8 __attribute__((ext_vector_type(8)));
typedef bf16  bf16x4 __attribute__((ext_vector_type(4)));
typedef float f32x16 __attribute__((ext_vector_type(16)));

__device__ __forceinline__ void async_cp16(const void* g, void* l) {
  __builtin_amdgcn_global_load_lds((const __attribute__((address_space(1))) void*)g,
                                   (__attribute__((address_space(3))) void*)l, 16, 0, 0);
}

// ---------------- zero out + control ints ----------------
__global__ __launch_bounds__(256) void zero_kernel(float4* __restrict__ out4, int n4,
                                                   int* __restrict__ ctrl) {
  const int i = blockIdx.x * 256 + threadIdx.x;
  if (i < n4) out4[i] = float4{0.f, 0.f, 0.f, 0.f};
  if (blockIdx.x == 0 && threadIdx.x < 64) ctrl[threadIdx.x] = 0;
}

// ---------------- fp32 -> bf16 convert ----------------
__global__ __launch_bounds__(256) void cvt_kernel(const float* __restrict__ in,
                                                  bf16* __restrict__ out, int n4) {
  const int i = blockIdx.x * 256 + threadIdx.x;
  if (i < n4) {
    const float4 v = ((const float4*)in)[i];
    bf16x4 o;
    o[0] = (bf16)v.x; o[1] = (bf16)v.y; o[2] = (bf16)v.z; o[3] = (bf16)v.w;
    ((bf16x4*)out)[i] = o;
  }
}

// ---------------- gating: fp32 logits, top-2, softmax ----------------
__global__ __launch_bounds__(64) void gate_kernel(const float* __restrict__ x,
                                                  const float* __restrict__ gw,
                                                  int* __restrict__ sel,
                                                  float* __restrict__ selw) {
  const int t = blockIdx.x;
  const int lane = threadIdx.x;
  const float* xr = x + (size_t)t * DIM;
  float acc[NEXP];
#pragma unroll
  for (int e = 0; e < NEXP; e++) acc[e] = 0.f;
  for (int i = lane; i < DIM; i += 64) {
    const float xv = xr[i];
#pragma unroll
    for (int e = 0; e < NEXP; e++) acc[e] += xv * gw[e * DIM + i];
  }
#pragma unroll
  for (int e = 0; e < NEXP; e++) {
#pragma unroll
    for (int m = 1; m < 64; m <<= 1) acc[e] += __shfl_xor(acc[e], m);
  }
  if (lane == 0) {
    int e0 = 0; float l0 = acc[0];
#pragma unroll
    for (int e = 1; e < NEXP; e++) if (acc[e] > l0) { l0 = acc[e]; e0 = e; }
    int e1 = -1; float l1 = -3.4e38f;
#pragma unroll
    for (int e = 0; e < NEXP; e++) if (e != e0 && acc[e] > l1) { l1 = acc[e]; e1 = e; }
    const float ex = expf(l1 - l0);            // l1 <= l0
    const float w0 = 1.f / (1.f + ex);
    sel[t * 2] = e0;  sel[t * 2 + 1] = e1;
    selw[t * 2] = w0; selw[t * 2 + 1] = 1.f - w0;
  }
}

// ---------------- per-expert counts ----------------
__global__ __launch_bounds__(256) void count_kernel(const int* __restrict__ sel,
                                                    int* __restrict__ counts) {
  const int i = blockIdx.x * 256 + threadIdx.x;
  const int lane = threadIdx.x & 63;
  const int e = sel[i];
#pragma unroll
  for (int ee = 0; ee < NEXP; ee++) {
    const unsigned long long mask = __ballot(e == ee);
    if (e == ee) {
      const int leader = __ffsll(mask) - 1;
      if (lane == leader) atomicAdd(&counts[ee], __popcll(mask));
    }
  }
}

// ---------------- segment offsets + tile map ----------------
__global__ void tilemap_kernel(const int* __restrict__ counts, int* __restrict__ segoff,
                               int* __restrict__ tile_e, int* __restrict__ tile_m,
                               int* __restrict__ ntiles) {
  if (threadIdx.x == 0 && blockIdx.x == 0) {
    int off = 0, nt = 0;
    for (int e = 0; e < NEXP; e++) {
      segoff[e] = off;
      const int c = counts[e];
      for (int m = 0; m < c; m += 128) { tile_e[nt] = e; tile_m[nt] = m; nt++; }
      off += c;
    }
    segoff[NEXP] = off;
    ntiles[0] = nt;
  }
}

// ---------------- fill gather lists ----------------
__global__ __launch_bounds__(256) void fill_kernel(const int* __restrict__ sel,
                                                   const float* __restrict__ selw,
                                                   const int* __restrict__ segoff,
                                                   int* __restrict__ fill,
                                                   int* __restrict__ tokl,
                                                   float* __restrict__ wl) {
  const int t = blockIdx.x * 256 + threadIdx.x;
  const int lane = threadIdx.x & 63;
#pragma unroll
  for (int s = 0; s < 2; s++) {
    const int e = sel[t * 2 + s];
    const float w = selw[t * 2 + s];
    for (int ee = 0; ee < NEXP; ee++) {
      const unsigned long long mask = __ballot(e == ee);
      if (e == ee) {
        const int leader = __ffsll(mask) - 1;
        const int cnt = __popcll(mask);
        int base = 0;
        if (lane == leader) base = atomicAdd(&fill[ee], cnt);
        base = __shfl(base, leader);
        const int pos = base + __popcll(mask & ((1ull << lane) - 1ull));
        const int idx = segoff[ee] + pos;
        tokl[idx] = t;
        wl[idx] = w;
      }
    }
  }
}

// ---------------- GEMM1 + SwiGLU: act = silu(Xe@w1^T) * (Xe@w3^T) ----------------
// BM=128, BN=128 (dual-B), BK=64. XOR-swizzled LDS: logical (row, cb) at
// physical (row, cb^(row&7)); 16B blocks. mfma_f32_32x32x16_bf16, C/D:
// col=lane&31, row=(reg&3)+8*(reg>>2)+4*(lane>>5).
// Per wave: 64x64 of h1 AND h3; per ks: 6 ds_read_b128, 8 MFMA.
__global__ __launch_bounds__(256) void gemm_act_kernel(
    const bf16* __restrict__ xb, const bf16* __restrict__ w1b, const bf16* __restrict__ w3b,
    const int* __restrict__ tokl, const int* __restrict__ counts, const int* __restrict__ segoff,
    const int* __restrict__ tile_e, const int* __restrict__ tile_m, const int* __restrict__ ntiles,
    bf16* __restrict__ act) {
  const int tile = blockIdx.y;
  if (tile >= *ntiles) return;
  const int e   = tile_e[tile];
  const int m0  = tile_m[tile];
  const int n0  = blockIdx.x * 128;
  const int Ne  = counts[e];
  const int seg = segoff[e];

  __shared__ bf16 As[128 * 64];
  __shared__ bf16 Bs1[128 * 64];
  __shared__ bf16 Bs3[128 * 64];

  const int tid = threadIdx.x;
  const int lane = tid & 63;
  const int wv = tid >> 6;
  const int sr = tid >> 3;               // staging row 0..31
  const int scb = (tid & 7) ^ (sr & 7);  // SWIZZLE: global col block for this lane's slot

  const bf16* aptr[4];
#pragma unroll
  for (int i = 0; i < 4; i++) {
    int m = m0 + sr + 32 * i; if (m > Ne - 1) m = Ne - 1;   // clamp tail
    aptr[i] = xb + (size_t)tokl[seg + m] * DIM + scb * 8;
  }
  const bf16 *b1p[4], *b3p[4];
#pragma unroll
  for (int i = 0; i < 4; i++) {
    const int n = n0 + sr + 32 * i;
    b1p[i] = w1b + ((size_t)e * HID + n) * DIM + scb * 8;
    b3p[i] = w3b + ((size_t)e * HID + n) * DIM + scb * 8;
  }

  f32x16 acc1[2][2], acc3[2][2];
#pragma unroll
  for (int i = 0; i < 2; i++)
#pragma unroll
    for (int j = 0; j < 2; j++)
#pragma unroll
      for (int r = 0; r < 16; r++) { acc1[i][j][r] = 0.f; acc3[i][j][r] = 0.f; }

  const int lwm = (wv & 1) * 64;
  const int lwn = (wv >> 1) * 64;
  const int l31 = lane & 31;
  const int lhi = lane >> 5;
  const int l7  = l31 & 7;

  for (int k0 = 0; k0 < DIM; k0 += 64) {
#pragma unroll
    for (int i = 0; i < 4; i++)
      async_cp16(aptr[i] + k0, (char*)As + i * 4096 + tid * 16);
#pragma unroll
    for (int i = 0; i < 4; i++) {
      async_cp16(b1p[i] + k0, (char*)Bs1 + i * 4096 + tid * 16);
      async_cp16(b3p[i] + k0, (char*)Bs3 + i * 4096 + tid * 16);
    }
    __syncthreads();
#pragma unroll
    for (int ks = 0; ks < 4; ks++) {
      const int swz = (((ks * 2 + lhi) ^ l7) * 8);   // swizzled col offset (elems)
      bf16x8 a0  = *(const bf16x8*)(As  + (lwm + l31) * 64 + swz);
      bf16x8 a1  = *(const bf16x8*)(As  + (lwm + 32 + l31) * 64 + swz);
      bf16x8 b10 = *(const bf16x8*)(Bs1 + (lwn + l31) * 64 + swz);
      bf16x8 b11 = *(const bf16x8*)(Bs1 + (lwn + 32 + l31) * 64 + swz);
      bf16x8 b30 = *(const bf16x8*)(Bs3 + (lwn + l31) * 64 + swz);
      bf16x8 b31 = *(const bf16x8*)(Bs3 + (lwn + 32 + l31) * 64 + swz);
      acc1[0][0] = __builtin_amdgcn_mfma_f32_32x32x16_bf16(a0, b10, acc1[0][0], 0, 0, 0);
      acc1[0][1] = __builtin_amdgcn_mfma_f32_32x32x16_bf16(a0, b11, acc1[0][1], 0, 0, 0);
      acc1[1][0] = __builtin_amdgcn_mfma_f32_32x32x16_bf16(a1, b10, acc1[1][0], 0, 0, 0);
      acc1[1][1] = __builtin_amdgcn_mfma_f32_32x32x16_bf16(a1, b11, acc1[1][1], 0, 0, 0);
      acc3[0][0] = __builtin_amdgcn_mfma_f32_32x32x16_bf16(a0, b30, acc3[0][0], 0, 0, 0);
      acc3[0][1] = __builtin_amdgcn_mfma_f32_32x32x16_bf16(a0, b31, acc3[0][1], 0, 0, 0);
      acc3[1][0] = __builtin_amdgcn_mfma_f32_32x32x16_bf16(a1, b30, acc3[1][0], 0, 0, 0);
      acc3[1][1] = __builtin_amdgcn_mfma_f32_32x32x16_bf16(a1, b31, acc3[1][1], 0, 0, 0);
    }
    __syncthreads();
  }

#pragma unroll
  for (int mi = 0; mi < 2; mi++) {
#pragma unroll
    for (int ni = 0; ni < 2; ni++) {
#pragma unroll
      for (int r = 0; r < 16; r++) {
        const int row = lwm + 32 * mi + (r & 3) + 8 * (r >> 2) + 4 * lhi;
        const int m = m0 + row;
        if (m < Ne) {
          const float h1 = acc1[mi][ni][r];
          const float h3 = acc3[mi][ni][r];
          const float sv = h1 / (1.f + __expf(-h1)) * h3;
          act[(size_t)(seg + m) * HID + (n0 + lwn + 32 * ni + l31)] = (bf16)sv;
        }
      }
    }
  }
}

// ---------------- GEMM2 + scatter: out[tok] += cw * (act @ w2^T) ----------------
// BM=128, BN=256, BK=64. Same XOR swizzle. Per wave: 64x128 out; per ks:
// 6 ds_read_b128, 8 MFMA.
__global__ __launch_bounds__(256) void gemm_out_kernel(
    const bf16* __restrict__ act, const bf16* __restrict__ w2b,
    const int* __restrict__ tokl, const float* __restrict__ wl,
    const int* __restrict__ counts, const int* __restrict__ segoff,
    const int* __restrict__ tile_e, const int* __restrict__ tile_m, const int* __restrict__ ntiles,
    float* __restrict__ out) {
  const int tile = blockIdx.y;
  if (tile >= *ntiles) return;
  const int e   = tile_e[tile];
  const int m0  = tile_m[tile];
  const int n0  = blockIdx.x * 256;
  const int Ne  = counts[e];
  const int seg = segoff[e];

  __shared__ bf16 As[128 * 64];
  __shared__ bf16 Bs[256 * 64];
  __shared__ int   sh_tok[128];
  __shared__ float sh_w[128];

  const int tid = threadIdx.x;
  const int lane = tid & 63;
  const int wv = tid >> 6;
  const int sr = tid >> 3;
  const int scb = (tid & 7) ^ (sr & 7);  // SWIZZLE

  if (tid < 128) {
    const int m = m0 + tid;
    if (m < Ne) { sh_tok[tid] = tokl[seg + m]; sh_w[tid] = wl[seg + m]; }
    else        { sh_tok[tid] = -1;            sh_w[tid] = 0.f; }
  }

  const bf16* aptr[4];
#pragma unroll
  for (int i = 0; i < 4; i++) {
    int m = m0 + sr + 32 * i; if (m > Ne - 1) m = Ne - 1;
    aptr[i] = act + (size_t)(seg + m) * HID + scb * 8;
  }
  const bf16* bptr[8];
#pragma unroll
  for (int i = 0; i < 8; i++) {
    const int d = n0 + sr + 32 * i;
    bptr[i] = w2b + ((size_t)e * DIM + d) * HID + scb * 8;
  }

  f32x16 acc[2][4];
#pragma unroll
  for (int i = 0; i < 2; i++)
#pragma unroll
    for (int j = 0; j < 4; j++)
#pragma unroll
      for (int r = 0; r < 16; r++) acc[i][j][r] = 0.f;

  const int lwm = (wv & 1) * 64;
  const int lwn = (wv >> 1) * 128;
  const int l31 = lane & 31;
  const int lhi = lane >> 5;
  const int l7  = l31 & 7;

  for (int k0 = 0; k0 < HID; k0 += 64) {
#pragma unroll
    for (int i = 0; i < 4; i++)
      async_cp16(aptr[i] + k0, (char*)As + i * 4096 + tid * 16);
#pragma unroll
    for (int i = 0; i < 8; i++)
      async_cp16(bptr[i] + k0, (char*)Bs + i * 4096 + tid * 16);
    __syncthreads();
#pragma unroll
    for (int ks = 0; ks < 4; ks++) {
      const int swz = (((ks * 2 + lhi) ^ l7) * 8);
      bf16x8 a0 = *(const bf16x8*)(As + (lwm + l31) * 64 + swz);
      bf16x8 a1 = *(const bf16x8*)(As + (lwm + 32 + l31) * 64 + swz);
      bf16x8 b0 = *(const bf16x8*)(Bs + (lwn + l31) * 64 + swz);
      bf16x8 b1 = *(const bf16x8*)(Bs + (lwn + 32 + l31) * 64 + swz);
      bf16x8 b2 = *(const bf16x8*)(Bs + (lwn + 64 + l31) * 64 + swz);
      bf16x8 b3 = *(const bf16x8*)(Bs + (lwn + 96 + l31) * 64 + swz);
      acc[0][0] = __builtin_amdgcn_mfma_f32_32x32x16_bf16(a0, b0, acc[0][0], 0, 0, 0);
      acc[0][1] = __builtin_amdgcn_mfma_f32_32x32x16_bf16(a0, b1, acc[0][1], 0, 0, 0);
      acc[0][2] = __builtin_amdgcn_mfma_f32_32x32x16_bf16(a0, b2, acc[0][2], 0, 0, 0);
      acc[0][3] = __builtin_amdgcn_mfma_f32_32x32x16_bf16(a0, b3, acc[0][3], 0, 0, 0);
      acc[1][0] = __builtin_amdgcn_mfma_f32_32x32x16_bf16(a1, b0, acc[1][0], 0, 0, 0);
      acc[1][1] = __builtin_amdgcn_mfma_f32_32x32x16_bf16(a1, b1, acc[1][1], 0, 0, 0);
      acc[1][2] = __builtin_amdgcn_mfma_f32_32x32x16_bf16(a1, b2, acc[1][2], 0, 0, 0);
      acc[1][3] = __builtin_amdgcn_mfma_f32_32x32x16_bf16(a1, b3, acc[1][3], 0, 0, 0);
    }
    __syncthreads();
  }

#pragma unroll
  for (int mi = 0; mi < 2; mi++) {
#pragma unroll
    for (int ni = 0; ni < 4; ni++) {
#pragma unroll
      for (int r = 0; r < 16; r++) {
        const int row = lwm + 32 * mi + (r & 3) + 8 * (r >> 2) + 4 * lhi;
        const int tok = sh_tok[row];
        if (tok >= 0) {
          const int col = n0 + lwn + 32 * ni + l31;
          atomicAdd(&out[(size_t)tok * DIM + col], sh_w[row] * acc[mi][ni][r]);
        }
      }
    }
  }
}

// ---------------- launch ----------------
extern "C" void kernel_launch(void* const* d_in, const int* in_sizes, int n_in,
                              void* d_out, int out_size, void* d_ws, size_t ws_size,
                              hipStream_t stream) {
  const float* x  = (const float*)d_in[0];
  const float* gw = (const float*)d_in[1];
  const float* w1 = (const float*)d_in[2];
  const float* w3 = (const float*)d_in[3];
  const float* w2 = (const float*)d_in[4];
  float* out = (float*)d_out;

  char* ws = (char*)d_ws;
  size_t off = 0;
  auto alloc = [&](size_t bytes) -> char* {
    char* p = ws + off; off += (bytes + 255) & ~(size_t)255; return p;
  };

  // --- small control buffers FIRST
  int* ctrl = (int*)alloc(4096);
  int* counts = ctrl;                   // [0..7]
  int* fill   = ctrl + 8;               // [8..15]
  int* segoff = ctrl + 16;              // [16..24]
  int* ntiles = ctrl + 32;              // [32]
  int* tile_e = ctrl + 64;              // [64..327]
  int* tile_m = ctrl + 512;             // [512..775]
  int*   sel  = (int*)alloc((size_t)T_TOK * 2 * 4);
  float* selw = (float*)alloc((size_t)T_TOK * 2 * 4);
  int*   tokl = (int*)alloc((size_t)2 * T_TOK * 4);
  float* wl   = (float*)alloc((size_t)2 * T_TOK * 4);

  // --- big buffers: 128 + 32 + 32 + 32 = 224 MiB
  bf16* act  = (bf16*)alloc((size_t)2 * T_TOK * HID * 2);      // 128 MiB
  bf16* w1b  = (bf16*)alloc((size_t)NEXP * HID * DIM * 2);     // 32 MiB
  bf16* w3b  = (bf16*)alloc((size_t)NEXP * HID * DIM * 2);     // 32 MiB
  bf16* xb   = (bf16*)alloc((size_t)T_TOK * DIM * 2);          // 32 MiB
  bf16* w2b  = xb;   // ALIAS: xb dead after gemm_act
  (void)ws_size; (void)in_sizes; (void)n_in; (void)out_size;

  zero_kernel<<<T_TOK * DIM / 4 / 256, 256, 0, stream>>>((float4*)out, T_TOK * DIM / 4, ctrl);

  cvt_kernel<<<16384, 256, 0, stream>>>(x,  xb,  T_TOK * DIM / 4);
  cvt_kernel<<<16384, 256, 0, stream>>>(w1, w1b, NEXP * HID * DIM / 4);
  cvt_kernel<<<16384, 256, 0, stream>>>(w3, w3b, NEXP * HID * DIM / 4);

  gate_kernel<<<T_TOK, 64, 0, stream>>>(x, gw, sel, selw);
  count_kernel<<<2 * T_TOK / 256, 256, 0, stream>>>(sel, counts);
  tilemap_kernel<<<1, 64, 0, stream>>>(counts, segoff, tile_e, tile_m, ntiles);
  fill_kernel<<<T_TOK / 256, 256, 0, stream>>>(sel, selw, segoff, fill, tokl, wl);

  gemm_act_kernel<<<dim3(HID / 128, MAX_TILES), 256, 0, stream>>>(
      xb, w1b, w3b, tokl, counts, segoff, tile_e, tile_m, ntiles, act);

  cvt_kernel<<<16384, 256, 0, stream>>>(w2, w2b, NEXP * DIM * HID / 4);  // overwrites xb

  gemm_out_kernel<<<dim3(DIM / 256, MAX_TILES), 256, 0, stream>>>(
      act, w2b, tokl, wl, counts, segoff, tile_e, tile_m, ntiles, out);
}

// Round 3
// 982.194 us; speedup vs baseline: 1.3087x; 1.3087x over previous
//
#include <hip/hip_runtime.h>
#include <hip/hip_bf16.h>
#include <cstdint>

// MoE SwiGLU: B=8 S=2048 D=1024 H=2048 E=8 K=2. T=16384 tokens.
// Routed (top-2 only) bf16-MFMA implementation; gating in fp32.
//
// R3: XOR-swizzled LDS (bank conflicts 2.4e8 -> 3.4e7).
// R5: FAILED (1285us): 128-AGPR acc + 2-barrier structure -> occupancy
//     22.6->11.4%, no latency hiding. Lesson: fat waves need intra-block
//     pipelining, not occupancy.
// R6: gemm_act rewritten as counted-vmcnt pipeline (T3/T4/T5):
//     BM=256, stacked B (w1/w3 interleaved by 32-col chunk), BK=64,
//     8 waves, per-wave 4x2 frags (0.75KB LDS read per MFMA -> ~66%
//     MfmaUtil ceiling vs 50% at 2x2). 4 phases/K-tile, vmcnt(2) only at
//     phase 0, raw s_barrier, setprio around MFMA cluster, 128KB dynamic
//     LDS dbuf. gemm_out + ancillary kernels: reverted to R4 (known-good).

#define T_TOK 16384
#define DIM   1024
#define HID   2048
#define NEXP  8
#define MAX_TILES 264    // 128-row tiles: sum ceil(Ne/128) <= 256 + 8
#define MAX_T256  136    // 256-row tiles: sum ceil(Ne/256) <= 128 + 8

typedef __bf16 bf16;
typedef bf16  bf16x8 __attribute__((ext_vector_type(8)));
typedef bf16  bf16x4 __attribute__((ext_vector_type(4)));
typedef float f32x16 __attribute__((ext_vector_type(16)));

__device__ __forceinline__ void async_cp16(const void* g, void* l) {
  __builtin_amdgcn_global_load_lds((const __attribute__((address_space(1))) void*)g,
                                   (__attribute__((address_space(3))) void*)l, 16, 0, 0);
}

// ---------------- zero out + control ints ----------------
__global__ __launch_bounds__(256) void zero_kernel(float4* __restrict__ out4, int n4,
                                                   int* __restrict__ ctrl) {
  const int i = blockIdx.x * 256 + threadIdx.x;
  if (i < n4) out4[i] = float4{0.f, 0.f, 0.f, 0.f};
  if (blockIdx.x == 0 && threadIdx.x < 64) ctrl[threadIdx.x] = 0;
}

// ---------------- fp32 -> bf16 convert ----------------
__global__ __launch_bounds__(256) void cvt_kernel(const float* __restrict__ in,
                                                  bf16* __restrict__ out, int n4) {
  const int i = blockIdx.x * 256 + threadIdx.x;
  if (i < n4) {
    const float4 v = ((const float4*)in)[i];
    bf16x4 o;
    o[0] = (bf16)v.x; o[1] = (bf16)v.y; o[2] = (bf16)v.z; o[3] = (bf16)v.w;
    ((bf16x4*)out)[i] = o;
  }
}

// ---------------- gating: fp32 logits, top-2, softmax ----------------
__global__ __launch_bounds__(64) void gate_kernel(const float* __restrict__ x,
                                                  const float* __restrict__ gw,
                                                  int* __restrict__ sel,
                                                  float* __restrict__ selw) {
  const int t = blockIdx.x;
  const int lane = threadIdx.x;
  const float* xr = x + (size_t)t * DIM;
  float acc[NEXP];
#pragma unroll
  for (int e = 0; e < NEXP; e++) acc[e] = 0.f;
  for (int i = lane; i < DIM; i += 64) {
    const float xv = xr[i];
#pragma unroll
    for (int e = 0; e < NEXP; e++) acc[e] += xv * gw[e * DIM + i];
  }
#pragma unroll
  for (int e = 0; e < NEXP; e++) {
#pragma unroll
    for (int m = 1; m < 64; m <<= 1) acc[e] += __shfl_xor(acc[e], m);
  }
  if (lane == 0) {
    int e0 = 0; float l0 = acc[0];
#pragma unroll
    for (int e = 1; e < NEXP; e++) if (acc[e] > l0) { l0 = acc[e]; e0 = e; }
    int e1 = -1; float l1 = -3.4e38f;
#pragma unroll
    for (int e = 0; e < NEXP; e++) if (e != e0 && acc[e] > l1) { l1 = acc[e]; e1 = e; }
    const float ex = expf(l1 - l0);            // l1 <= l0
    const float w0 = 1.f / (1.f + ex);
    sel[t * 2] = e0;  sel[t * 2 + 1] = e1;
    selw[t * 2] = w0; selw[t * 2 + 1] = 1.f - w0;
  }
}

// ---------------- per-expert counts ----------------
__global__ __launch_bounds__(256) void count_kernel(const int* __restrict__ sel,
                                                    int* __restrict__ counts) {
  const int i = blockIdx.x * 256 + threadIdx.x;
  const int lane = threadIdx.x & 63;
  const int e = sel[i];
#pragma unroll
  for (int ee = 0; ee < NEXP; ee++) {
    const unsigned long long mask = __ballot(e == ee);
    if (e == ee) {
      const int leader = __ffsll(mask) - 1;
      if (lane == leader) atomicAdd(&counts[ee], __popcll(mask));
    }
  }
}

// ---------------- segment offsets + tile maps (128-row and 256-row) ----------------
__global__ void tilemap_kernel(const int* __restrict__ counts, int* __restrict__ segoff,
                               int* __restrict__ tile_e, int* __restrict__ tile_m,
                               int* __restrict__ ntiles,
                               int* __restrict__ tile_e2, int* __restrict__ tile_m2,
                               int* __restrict__ ntiles2) {
  if (threadIdx.x == 0 && blockIdx.x == 0) {
    int off = 0, nt = 0, nt2 = 0;
    for (int e = 0; e < NEXP; e++) {
      segoff[e] = off;
      const int c = counts[e];
      for (int m = 0; m < c; m += 128) { tile_e[nt] = e; tile_m[nt] = m; nt++; }
      for (int m = 0; m < c; m += 256) { tile_e2[nt2] = e; tile_m2[nt2] = m; nt2++; }
      off += c;
    }
    segoff[NEXP] = off;
    ntiles[0] = nt;
    ntiles2[0] = nt2;
  }
}

// ---------------- fill gather lists ----------------
__global__ __launch_bounds__(256) void fill_kernel(const int* __restrict__ sel,
                                                   const float* __restrict__ selw,
                                                   const int* __restrict__ segoff,
                                                   int* __restrict__ fill,
                                                   int* __restrict__ tokl,
                                                   float* __restrict__ wl) {
  const int t = blockIdx.x * 256 + threadIdx.x;
  const int lane = threadIdx.x & 63;
#pragma unroll
  for (int s = 0; s < 2; s++) {
    const int e = sel[t * 2 + s];
    const float w = selw[t * 2 + s];
    for (int ee = 0; ee < NEXP; ee++) {
      const unsigned long long mask = __ballot(e == ee);
      if (e == ee) {
        const int leader = __ffsll(mask) - 1;
        const int cnt = __popcll(mask);
        int base = 0;
        if (lane == leader) base = atomicAdd(&fill[ee], cnt);
        base = __shfl(base, leader);
        const int pos = base + __popcll(mask & ((1ull << lane) - 1ull));
        const int idx = segoff[ee] + pos;
        tokl[idx] = t;
        wl[idx] = w;
      }
    }
  }
}

// ---------------- GEMM1 + SwiGLU (pipelined): act = silu(Xe@w1^T)*(Xe@w3^T) ----
// BM=256 tokens, 128 real cols (stacked-B 256 LDS rows: per 64-row group i:
// rows [64i,64i+32) = w1 cols [n0+32i..), rows [64i+32,64i+64) = w3 same cols).
// BK=64. 8 waves: wm=wv>>2 (2 M-halves of 128), wn=wv&3 (4 col-chunks of 32).
// Per wave acc[4][2]: [mi][0]=h1, [mi][1]=h3 for its 32 cols. XOR swizzle:
// physical (row, cb) holds logical cb^(row&7), 16B blocks, same as R4.
// K-loop: 16 tiles x 4 phases; per phase: 2 prefetch gload_lds (next tile),
// phase0: s_waitcnt vmcnt(2)+s_barrier (never drain to 0); 6 ds_read_b128;
// setprio(1); 8 MFMA; setprio(0); s_barrier. 128KB dynamic LDS dbuf.
__global__ __launch_bounds__(512, 2) void gemm_act_kernel(
    const bf16* __restrict__ xb, const bf16* __restrict__ w1b, const bf16* __restrict__ w3b,
    const int* __restrict__ tokl, const int* __restrict__ counts, const int* __restrict__ segoff,
    const int* __restrict__ tile_e2, const int* __restrict__ tile_m2, const int* __restrict__ ntiles2,
    bf16* __restrict__ act) {
  const int tile = blockIdx.y;
  if (tile >= *ntiles2) return;
  const int e   = tile_e2[tile];
  const int m0  = tile_m2[tile];
  const int n0  = blockIdx.x * 128;
  const int Ne  = counts[e];
  const int seg = segoff[e];

  extern __shared__ char smem[];   // [2][A 32KB | B 32KB] = 128KB

  const int tid  = threadIdx.x;
  const int lane = tid & 63;
  const int wv   = tid >> 6;
  const int sr   = tid >> 3;               // staging row 0..63
  const int scb  = (tid & 7) ^ (sr & 7);   // swizzled global col-block

  // A gather pointers: rows m0 + sr + 64*i (clamped)
  const bf16* aptr[4];
#pragma unroll
  for (int i = 0; i < 4; i++) {
    int m = m0 + sr + 64 * i; if (m > Ne - 1) m = Ne - 1;
    aptr[i] = xb + (size_t)tokl[seg + m] * DIM + scb * 8;
  }
  // Stacked-B pointers: instr i covers stacked rows [64i, 64i+64):
  // half=(sr>>5)&1 selects w1/w3; col = n0 + 32*i + (sr&31)
  const bf16* bptr[4];
#pragma unroll
  for (int i = 0; i < 4; i++) {
    const bf16* wsel = ((sr >> 5) & 1) ? w3b : w1b;
    bptr[i] = wsel + ((size_t)e * HID + n0 + 32 * i + (sr & 31)) * DIM + scb * 8;
  }

  f32x16 acc[4][2];
#pragma unroll
  for (int i = 0; i < 4; i++)
#pragma unroll
    for (int j = 0; j < 2; j++)
#pragma unroll
      for (int r = 0; r < 16; r++) acc[i][j][r] = 0.f;

  const int wmBase = (wv >> 2) * 128;      // M base within 256
  const int wnBase = (wv & 3) * 64;        // stacked-N base
  const int l31 = lane & 31;
  const int lhi = lane >> 5;
  const int l7  = l31 & 7;

  // prologue: stage tile 0 into buf 0
#pragma unroll
  for (int i = 0; i < 4; i++) {
    async_cp16(aptr[i],          smem +         i * 8192 + tid * 16);
    async_cp16(bptr[i],          smem + 32768 + i * 8192 + tid * 16);
  }

  for (int t = 0; t < DIM / 64; ++t) {
    const bf16* Acur = (const bf16*)(smem + (t & 1) * 65536);
    const bf16* Bcur = Acur + 16384;
    char* Anx = smem + ((t + 1) & 1) * 65536;
    char* Bnx = Anx + 32768;
    const int kn = (t < DIM / 64 - 1 ? t + 1 : t) * 64;   // last iter: redundant restage
#pragma unroll
    for (int ks = 0; ks < 4; ++ks) {
      // prefetch pair for next tile (into the other buffer)
      async_cp16(aptr[ks] + kn, Anx + ks * 8192 + tid * 16);
      async_cp16(bptr[ks] + kn, Bnx + ks * 8192 + tid * 16);
      if (ks == 0) {
        // wait current tile's 8 loads (2 newest = just-issued prefetch remain)
        asm volatile("s_waitcnt vmcnt(2)\n\ts_barrier" ::: "memory");
      }
      const int swz = (((ks * 2 + lhi) ^ l7) * 8);
      bf16x8 a0 = *(const bf16x8*)(Acur + (wmBase +  0 + l31) * 64 + swz);
      bf16x8 a1 = *(const bf16x8*)(Acur + (wmBase + 32 + l31) * 64 + swz);
      bf16x8 a2 = *(const bf16x8*)(Acur + (wmBase + 64 + l31) * 64 + swz);
      bf16x8 a3 = *(const bf16x8*)(Acur + (wmBase + 96 + l31) * 64 + swz);
      bf16x8 b0 = *(const bf16x8*)(Bcur + (wnBase +  0 + l31) * 64 + swz);
      bf16x8 b1 = *(const bf16x8*)(Bcur + (wnBase + 32 + l31) * 64 + swz);
      __builtin_amdgcn_s_setprio(1);
      acc[0][0] = __builtin_amdgcn_mfma_f32_32x32x16_bf16(a0, b0, acc[0][0], 0, 0, 0);
      acc[0][1] = __builtin_amdgcn_mfma_f32_32x32x16_bf16(a0, b1, acc[0][1], 0, 0, 0);
      acc[1][0] = __builtin_amdgcn_mfma_f32_32x32x16_bf16(a1, b0, acc[1][0], 0, 0, 0);
      acc[1][1] = __builtin_amdgcn_mfma_f32_32x32x16_bf16(a1, b1, acc[1][1], 0, 0, 0);
      acc[2][0] = __builtin_amdgcn_mfma_f32_32x32x16_bf16(a2, b0, acc[2][0], 0, 0, 0);
      acc[2][1] = __builtin_amdgcn_mfma_f32_32x32x16_bf16(a2, b1, acc[2][1], 0, 0, 0);
      acc[3][0] = __builtin_amdgcn_mfma_f32_32x32x16_bf16(a3, b0, acc[3][0], 0, 0, 0);
      acc[3][1] = __builtin_amdgcn_mfma_f32_32x32x16_bf16(a3, b1, acc[3][1], 0, 0, 0);
      __builtin_amdgcn_s_setprio(0);
      asm volatile("s_barrier" ::: "memory");
    }
  }

  // epilogue: silu(h1)*h3 for this wave's 32 cols
  const int col = n0 + (wv & 3) * 32 + l31;
#pragma unroll
  for (int mi = 0; mi < 4; mi++) {
#pragma unroll
    for (int r = 0; r < 16; r++) {
      const int row = wmBase + 32 * mi + (r & 3) + 8 * (r >> 2) + 4 * lhi;
      const int m = m0 + row;
      if (m < Ne) {
        const float h1 = acc[mi][0][r];
        const float h3 = acc[mi][1][r];
        const float sv = h1 / (1.f + __expf(-h1)) * h3;
        act[(size_t)(seg + m) * HID + col] = (bf16)sv;
      }
    }
  }
}

// ---------------- GEMM2 + scatter: out[tok] += cw * (act @ w2^T) ----------------
// R4 version: BM=128, BN=128, BK=64, 2-barrier structure, XOR swizzle.
__global__ __launch_bounds__(256) void gemm_out_kernel(
    const bf16* __restrict__ act, const bf16* __restrict__ w2b,
    const int* __restrict__ tokl, const float* __restrict__ wl,
    const int* __restrict__ counts, const int* __restrict__ segoff,
    const int* __restrict__ tile_e, const int* __restrict__ tile_m, const int* __restrict__ ntiles,
    float* __restrict__ out) {
  const int tile = blockIdx.y;
  if (tile >= *ntiles) return;
  const int e   = tile_e[tile];
  const int m0  = tile_m[tile];
  const int n0  = blockIdx.x * 128;
  const int Ne  = counts[e];
  const int seg = segoff[e];

  __shared__ bf16 As[128 * 64];
  __shared__ bf16 Bs[128 * 64];
  __shared__ int   sh_tok[128];
  __shared__ float sh_w[128];

  const int tid = threadIdx.x;
  const int lane = tid & 63;
  const int wv = tid >> 6;
  const int sr = tid >> 3;
  const int scb = (tid & 7) ^ (sr & 7);  // SWIZZLE

  if (tid < 128) {
    const int m = m0 + tid;
    if (m < Ne) { sh_tok[tid] = tokl[seg + m]; sh_w[tid] = wl[seg + m]; }
    else        { sh_tok[tid] = -1;            sh_w[tid] = 0.f; }
  }

  const bf16* aptr[4];
#pragma unroll
  for (int i = 0; i < 4; i++) {
    int m = m0 + sr + 32 * i; if (m > Ne - 1) m = Ne - 1;
    aptr[i] = act + (size_t)(seg + m) * HID + scb * 8;
  }
  const bf16* bptr[4];
#pragma unroll
  for (int i = 0; i < 4; i++) {
    const int d = n0 + sr + 32 * i;
    bptr[i] = w2b + ((size_t)e * DIM + d) * HID + scb * 8;
  }

  f32x16 acc[4];
#pragma unroll
  for (int i = 0; i < 4; i++)
#pragma unroll
    for (int j = 0; j < 16; j++) acc[i][j] = 0.f;

  const int lwm = (wv & 1) * 64;
  const int lwn = (wv >> 1) * 64;
  const int l31 = lane & 31;
  const int lhi = lane >> 5;
  const int l7  = l31 & 7;

  for (int k0 = 0; k0 < HID; k0 += 64) {
#pragma unroll
    for (int i = 0; i < 4; i++)
      async_cp16(aptr[i] + k0, (char*)As + i * 4096 + tid * 16);
#pragma unroll
    for (int i = 0; i < 4; i++)
      async_cp16(bptr[i] + k0, (char*)Bs + i * 4096 + tid * 16);
    __syncthreads();
#pragma unroll
    for (int ks = 0; ks < 4; ks++) {
      const int swz = (((ks * 2 + lhi) ^ l7) * 8);
      bf16x8 a0 = *(const bf16x8*)(As + (lwm + l31) * 64 + swz);
      bf16x8 a1 = *(const bf16x8*)(As + (lwm + 32 + l31) * 64 + swz);
      bf16x8 b0 = *(const bf16x8*)(Bs + (lwn + l31) * 64 + swz);
      bf16x8 b1 = *(const bf16x8*)(Bs + (lwn + 32 + l31) * 64 + swz);
      acc[0] = __builtin_amdgcn_mfma_f32_32x32x16_bf16(a0, b0, acc[0], 0, 0, 0);
      acc[1] = __builtin_amdgcn_mfma_f32_32x32x16_bf16(a0, b1, acc[1], 0, 0, 0);
      acc[2] = __builtin_amdgcn_mfma_f32_32x32x16_bf16(a1, b0, acc[2], 0, 0, 0);
      acc[3] = __builtin_amdgcn_mfma_f32_32x32x16_bf16(a1, b1, acc[3], 0, 0, 0);
    }
    __syncthreads();
  }

#pragma unroll
  for (int mi = 0; mi < 2; mi++) {
#pragma unroll
    for (int ni = 0; ni < 2; ni++) {
#pragma unroll
      for (int r = 0; r < 16; r++) {
        const int row = lwm + 32 * mi + (r & 3) + 8 * (r >> 2) + 4 * lhi;
        const int tok = sh_tok[row];
        if (tok >= 0) {
          const int col = n0 + lwn + 32 * ni + l31;
          atomicAdd(&out[(size_t)tok * DIM + col], sh_w[row] * acc[mi * 2 + ni][r]);
        }
      }
    }
  }
}

// ---------------- launch ----------------
extern "C" void kernel_launch(void* const* d_in, const int* in_sizes, int n_in,
                              void* d_out, int out_size, void* d_ws, size_t ws_size,
                              hipStream_t stream) {
  const float* x  = (const float*)d_in[0];
  const float* gw = (const float*)d_in[1];
  const float* w1 = (const float*)d_in[2];
  const float* w3 = (const float*)d_in[3];
  const float* w2 = (const float*)d_in[4];
  float* out = (float*)d_out;

  char* ws = (char*)d_ws;
  size_t off = 0;
  auto alloc = [&](size_t bytes) -> char* {
    char* p = ws + off; off += (bytes + 255) & ~(size_t)255; return p;
  };

  // --- small control buffers FIRST
  int* ctrl = (int*)alloc(8192);
  int* counts  = ctrl;                  // [0..7]
  int* fill    = ctrl + 8;              // [8..15]
  int* segoff  = ctrl + 16;             // [16..24]
  int* ntiles  = ctrl + 32;             // [32]
  int* ntiles2 = ctrl + 33;             // [33]
  int* tile_e  = ctrl + 64;             // [64..327]
  int* tile_m  = ctrl + 512;            // [512..775]
  int* tile_e2 = ctrl + 1024;           // [1024..1159]
  int* tile_m2 = ctrl + 1536;           // [1536..1671]
  int*   sel  = (int*)alloc((size_t)T_TOK * 2 * 4);
  float* selw = (float*)alloc((size_t)T_TOK * 2 * 4);
  int*   tokl = (int*)alloc((size_t)2 * T_TOK * 4);
  float* wl   = (float*)alloc((size_t)2 * T_TOK * 4);

  // --- big buffers: 128 + 32 + 32 + 32 = 224 MiB
  bf16* act  = (bf16*)alloc((size_t)2 * T_TOK * HID * 2);      // 128 MiB
  bf16* w1b  = (bf16*)alloc((size_t)NEXP * HID * DIM * 2);     // 32 MiB
  bf16* w3b  = (bf16*)alloc((size_t)NEXP * HID * DIM * 2);     // 32 MiB
  bf16* xb   = (bf16*)alloc((size_t)T_TOK * DIM * 2);          // 32 MiB
  bf16* w2b  = xb;   // ALIAS: xb dead after gemm_act
  (void)ws_size; (void)in_sizes; (void)n_in; (void)out_size;

  // allow 128KB dynamic LDS for the pipelined GEMM1
  hipFuncSetAttribute((const void*)gemm_act_kernel,
                      hipFuncAttributeMaxDynamicSharedMemorySize, 131072);

  zero_kernel<<<T_TOK * DIM / 4 / 256, 256, 0, stream>>>((float4*)out, T_TOK * DIM / 4, ctrl);

  cvt_kernel<<<16384, 256, 0, stream>>>(x,  xb,  T_TOK * DIM / 4);
  cvt_kernel<<<16384, 256, 0, stream>>>(w1, w1b, NEXP * HID * DIM / 4);
  cvt_kernel<<<16384, 256, 0, stream>>>(w3, w3b, NEXP * HID * DIM / 4);

  gate_kernel<<<T_TOK, 64, 0, stream>>>(x, gw, sel, selw);
  count_kernel<<<2 * T_TOK / 256, 256, 0, stream>>>(sel, counts);
  tilemap_kernel<<<1, 64, 0, stream>>>(counts, segoff, tile_e, tile_m, ntiles,
                                       tile_e2, tile_m2, ntiles2);
  fill_kernel<<<T_TOK / 256, 256, 0, stream>>>(sel, selw, segoff, fill, tokl, wl);

  gemm_act_kernel<<<dim3(HID / 128, MAX_T256), 512, 131072, stream>>>(
      xb, w1b, w3b, tokl, counts, segoff, tile_e2, tile_m2, ntiles2, act);

  cvt_kernel<<<16384, 256, 0, stream>>>(w2, w2b, NEXP * DIM * HID / 4);  // overwrites xb

  gemm_out_kernel<<<dim3(DIM / 128, MAX_TILES), 256, 0, stream>>>(
      act, w2b, tokl, wl, counts, segoff, tile_e, tile_m, ntiles, out);
}